// Round 6
// baseline (586.226 us; speedup 1.0000x reference)
//
#include <hip/hip_runtime.h>
#include <hip/hip_bf16.h>

typedef unsigned int   uint;
typedef unsigned short ushort;

#define NB   8
#define NC   64
#define LL   32768
#define KK   5
#define NG   4
#define NDG  2
#define NGD  8        // NG*NDG
#define NCD  8        // NC / NGD
#define NOFF 40       // NGD*KK
#define DWK  7

__device__ __forceinline__ float bits2f(uint u) {
  union { uint u; float f; } v; v.u = u; return v.f;
}
__device__ __forceinline__ float bf2f(ushort u) {
  union { uint u; float f; } v; v.u = ((uint)u) << 16; return v.f;
}
__device__ __forceinline__ ushort f2bf(float f) {   // round-to-nearest-even
  union { float f; uint u; } v; v.f = f;
  uint r = (v.u + 0x7fffu + ((v.u >> 16) & 1u)) >> 16;
  return (ushort)r;
}
__device__ __forceinline__ void unpack8(uint ux, uint uy, uint uz, uint uw,
                                        float* xv)
{
  xv[0] = bits2f(ux << 16); xv[1] = bits2f(ux & 0xffff0000u);
  xv[2] = bits2f(uy << 16); xv[3] = bits2f(uy & 0xffff0000u);
  xv[4] = bits2f(uz << 16); xv[5] = bits2f(uz & 0xffff0000u);
  xv[6] = bits2f(uw << 16); xv[7] = bits2f(uw & 0xffff0000u);
}

// ---------------------------------------------------------------------------
// k_stats: one f32 x pass, depthwise conv7 both branches, ONLY row stats
// (sum, sumsq per branch). No stores of y. One block per (b,c) row.
// ---------------------------------------------------------------------------
__device__ __forceinline__ void load8f(float* dst, const float* __restrict__ row,
                                       int start)
{
  if (start >= 0 && start + 8 <= LL) {
    float4 a = *(const float4*)(row + start);
    float4 b = *(const float4*)(row + start + 4);
    dst[0] = a.x; dst[1] = a.y; dst[2] = a.z; dst[3] = a.w;
    dst[4] = b.x; dst[5] = b.y; dst[6] = b.z; dst[7] = b.w;
  } else {
#pragma unroll
    for (int j = 0; j < 8; ++j) {
      int p = start + j;
      dst[j] = (p >= 0 && p < LL) ? row[p] : 0.f;
    }
  }
}

__global__ __launch_bounds__(256) void k_stats(
    const float* __restrict__ x,
    const float* __restrict__ dwAw, const float* __restrict__ dwAb,
    const float* __restrict__ dwMw, const float* __restrict__ dwMb,
    float4* __restrict__ partial)
{
  int tid = threadIdx.x;
  int bc  = blockIdx.x;           // b*64 + c
  int c   = bc & 63;
  const float* row = x + (size_t)bc * LL;

  float wa[DWK], wm[DWK];
#pragma unroll
  for (int j = 0; j < DWK; ++j) {
    wa[j] = dwAw[c * DWK + j];
    wm[j] = dwMw[c * DWK + j];
  }
  float ba = dwAb[c], bm = dwMb[c];

  float sa = 0.f, qa = 0.f, sm = 0.f, qm = 0.f;
  for (int it = 0; it < 16; ++it) {
    int m = it * 256 + tid;
    int lb = m * 8;
    float v[24];
    load8f(v + 0,  row, lb - 8);
    load8f(v + 8,  row, lb);
    load8f(v + 16, row, lb + 8);
#pragma unroll
    for (int u = 0; u < 8; ++u) {
      float ya = ba, ym = bm;
#pragma unroll
      for (int j = 0; j < DWK; ++j) {
        float xv = v[5 + u + j];
        ya += wa[j] * xv;
        ym += wm[j] * xv;
      }
      sa += ya; qa += ya * ya;
      sm += ym; qm += ym * ym;
    }
  }

  __shared__ float4 red[256];
  red[tid] = make_float4(sa, qa, sm, qm);
  __syncthreads();
  for (int s = 128; s > 0; s >>= 1) {
    if (tid < s) {
      float4 a = red[tid], b = red[tid + s];
      red[tid] = make_float4(a.x + b.x, a.y + b.y, a.z + b.z, a.w + b.w);
    }
    __syncthreads();
  }
  if (tid == 0) partial[bc] = red[0];
}

// ---------------------------------------------------------------------------
// k_xpose: x (b,c,l) f32 -> xT (b, gd, l, 8ch) bf16 packed (16 B per tap).
// ---------------------------------------------------------------------------
__global__ __launch_bounds__(256) void k_xpose(
    const float* __restrict__ x, ushort* __restrict__ xT)
{
  __shared__ __align__(16) float tile[8 * 256];
  int tid = threadIdx.x;
  int l0  = (blockIdx.x & 127) << 8;
  int gd  = (blockIdx.x >> 7) & 7;
  int b   = blockIdx.x >> 10;
  const float* src = x + (size_t)(b * NC + gd * 8) * LL + l0;
#pragma unroll
  for (int i = 0; i < 2; ++i) {
    int fid = i * 256 + tid;          // 512 float4 = 8 rows x 64 float4
    int c = fid >> 6, q = fid & 63;
    *(float4*)(tile + c * 256 + q * 4) =
        *(const float4*)(src + (size_t)c * LL + q * 4);
  }
  __syncthreads();
  uint4 pk;
  pk.x = (uint)f2bf(tile[0 * 256 + tid]) | ((uint)f2bf(tile[1 * 256 + tid]) << 16);
  pk.y = (uint)f2bf(tile[2 * 256 + tid]) | ((uint)f2bf(tile[3 * 256 + tid]) << 16);
  pk.z = (uint)f2bf(tile[4 * 256 + tid]) | ((uint)f2bf(tile[5 * 256 + tid]) << 16);
  pk.w = (uint)f2bf(tile[6 * 256 + tid]) | ((uint)f2bf(tile[7 * 256 + tid]) << 16);
  *(uint4*)(xT + ((size_t)(b * 8 + gd) * LL + l0 + tid) * 8) = pk;
}

// ---------------------------------------------------------------------------
// k_fin2: blocks 0..7 = per-batch GN fold into quarter-split pointwise
// weights:  wQA[((b*4+q)*64+c)*12 + j] = 4*pwA[(q*10+j)*64+c]*gA(b,c)
//           bAf[b*40+o] = 4*(pbA[o] + sum_c pwA[o*64+c]*cA(b,c));  M: scale 1.
// block 8 = main-conv weight permute wtW.
// ---------------------------------------------------------------------------
__global__ __launch_bounds__(256) void k_fin2(
    const float4* __restrict__ partial,
    const float* __restrict__ gnAw, const float* __restrict__ gnAb,
    const float* __restrict__ gnMw, const float* __restrict__ gnMb,
    const float* __restrict__ pwA, const float* __restrict__ pwM,
    const float* __restrict__ pbA, const float* __restrict__ pbM,
    const float* __restrict__ mw,
    float* __restrict__ wQA, float* __restrict__ wQM,
    float* __restrict__ bAf, float* __restrict__ bMf,
    float* __restrict__ wtW)
{
  int t = threadIdx.x;
  if (blockIdx.x == 8) {
    for (int j = t; j < 5120; j += 256) {
      int o = j & 15; int tt = j >> 4;
      int k = tt % 5;  tt /= 5;
      int c = tt % 8;  tt /= 8;
      int d = tt & 1;  int g = tt >> 1;
      wtW[j] = mw[((g * 16 + o) * 16 + d * 8 + c) * KK + k];
    }
    return;
  }
  int b = blockIdx.x;
  __shared__ float gA[64], cA[64], gM[64], cM[64];
  if (t < 64) {
    float4 v = partial[b * 64 + t];
    float mua = v.x / LL, vara = v.y / LL - mua * mua;
    float mum = v.z / LL, varm = v.w / LL - mum * mum;
    float ga = gnAw[t] * rsqrtf(vara + 1e-5f);
    float gm = gnMw[t] * rsqrtf(varm + 1e-5f);
    gA[t] = ga; cA[t] = gnAb[t] - mua * ga;
    gM[t] = gm; cM[t] = gnMb[t] - mum * gm;
  }
  __syncthreads();
  for (int idx = t; idx < 2560; idx += 256) {
    int q = idx / 640;
    int r = idx - q * 640;
    int c = r / 10;
    int j = r - c * 10;
    int o = q * 10 + j;
    wQA[((size_t)((b * 4 + q) * 64 + c)) * 12 + j] = 4.f * pwA[o * 64 + c] * gA[c];
    wQM[((size_t)((b * 4 + q) * 64 + c)) * 12 + j] = pwM[o * 64 + c] * gM[c];
  }
  if (t < 40) {
    float sA = 0.f, sM = 0.f;
    for (int c = 0; c < 64; ++c) {
      sA += pwA[t * 64 + c] * cA[c];
      sM += pwM[t * 64 + c] * cM[c];
    }
    bAf[b * 40 + t] = 4.f * (pbA[t] + sA);
    bMf[b * 40 + t] = pbM[t] + sM;
  }
}

// ---------------------------------------------------------------------------
// k_pd: per (b, 128-l tile), 512 threads:
//  phase 0: stage xT tile [l0-8, l0+136) into LDS (packed uint4/position)
//  phase 1: inline depthwise conv7 (both branches) -> raw y tiles (bf16 LDS)
//  phase 2: quarter-split matvec (GN folded) -> offs[10] + softmax attn[10]
//  phase 3: deform gather + grouped conv for this thread's group -> out
// ---------------------------------------------------------------------------
__global__ __launch_bounds__(512, 4) void k_pd(
    const ushort* __restrict__ xT,
    const float* __restrict__ dwAw, const float* __restrict__ dwAb,
    const float* __restrict__ dwMw, const float* __restrict__ dwMb,
    const float* __restrict__ wQA, const float* __restrict__ wQM,
    const float* __restrict__ bAf, const float* __restrict__ bMf,
    const float* __restrict__ wtW, const float* __restrict__ bias,
    float* __restrict__ out)
{
  __shared__ __align__(16) ushort s_x[8 * 144 * 8];   // 18.4 KB
  __shared__ ushort s_hA[64 * 128];                   // 16 KB
  __shared__ ushort s_hM[64 * 128];                   // 16 KB

  int t  = threadIdx.x;
  int b  = blockIdx.x >> 8;
  int l0 = (blockIdx.x & 255) << 7;
  const ushort* xTb = xT + (size_t)b * 8 * LL * 8;

  // ---- phase 0: stage x tile ----
  for (int fid = t; fid < 1152; fid += 512) {
    int gd = fid / 144, q = fid - gd * 144;
    int l  = l0 - 8 + q;
    uint4 v = make_uint4(0u, 0u, 0u, 0u);
    if (l >= 0 && l < LL)
      v = *(const uint4*)(xTb + ((size_t)gd * LL + l) * 8);
    *(uint4*)(s_x + (size_t)(gd * 144 + q) * 8) = v;
  }
  __syncthreads();

  // ---- phase 1: conv both branches ----
  {
    int gd = t >> 6;              // wave-uniform
    int s  = t & 63;
#pragma unroll
    for (int j = 0; j < 2; ++j) {
      int pos = s + 64 * j;
      float aA[8], aM[8];
#pragma unroll
      for (int i = 0; i < 8; ++i) {
        aA[i] = dwAb[gd * 8 + i];
        aM[i] = dwMb[gd * 8 + i];
      }
#pragma unroll
      for (int tap = 0; tap < DWK; ++tap) {
        uint4 u = *(const uint4*)(s_x + (size_t)(gd * 144 + 5 + pos + tap) * 8);
        float xv[8];
        unpack8(u.x, u.y, u.z, u.w, xv);
#pragma unroll
        for (int i = 0; i < 8; ++i) {
          aA[i] += dwAw[(gd * 8 + i) * DWK + tap] * xv[i];
          aM[i] += dwMw[(gd * 8 + i) * DWK + tap] * xv[i];
        }
      }
#pragma unroll
      for (int i = 0; i < 8; ++i) {
        s_hA[(gd * 8 + i) * 128 + pos] = f2bf(aA[i]);
        s_hM[(gd * 8 + i) * 128 + pos] = f2bf(aM[i]);
      }
    }
  }
  __syncthreads();

  // ---- phase 2: quarter-split matvec + softmax ----
  int pos = t & 127;
  int g   = t >> 7;               // group owned by this thread (wave-uniform)
  float offs[10], attn[10];
  {
    float acc[10];
    const float* bb = bAf + b * 40 + g * 10;
#pragma unroll
    for (int o = 0; o < 10; ++o) acc[o] = bb[o];
    const float* wbase = wQA + ((size_t)(b * 4 + g) * 64) * 12;
    for (int c = 0; c < NC; ++c) {
      float hv = bf2f(s_hA[c * 128 + pos]);
      const float* wr = wbase + c * 12;
      float4 w0 = *(const float4*)(wr);
      float4 w1 = *(const float4*)(wr + 4);
      float2 w2 = *(const float2*)(wr + 8);
      acc[0] += w0.x * hv; acc[1] += w0.y * hv;
      acc[2] += w0.z * hv; acc[3] += w0.w * hv;
      acc[4] += w1.x * hv; acc[5] += w1.y * hv;
      acc[6] += w1.z * hv; acc[7] += w1.w * hv;
      acc[8] += w2.x * hv; acc[9] += w2.y * hv;
    }
#pragma unroll
    for (int o = 0; o < 10; ++o) offs[o] = acc[o];
  }
  {
    float acc[10];
    const float* bb = bMf + b * 40 + g * 10;
#pragma unroll
    for (int o = 0; o < 10; ++o) acc[o] = bb[o];
    const float* wbase = wQM + ((size_t)(b * 4 + g) * 64) * 12;
    for (int c = 0; c < NC; ++c) {
      float hv = bf2f(s_hM[c * 128 + pos]);
      const float* wr = wbase + c * 12;
      float4 w0 = *(const float4*)(wr);
      float4 w1 = *(const float4*)(wr + 4);
      float2 w2 = *(const float2*)(wr + 8);
      acc[0] += w0.x * hv; acc[1] += w0.y * hv;
      acc[2] += w0.z * hv; acc[3] += w0.w * hv;
      acc[4] += w1.x * hv; acc[5] += w1.y * hv;
      acc[6] += w1.z * hv; acc[7] += w1.w * hv;
      acc[8] += w2.x * hv; acc[9] += w2.y * hv;
    }
#pragma unroll
    for (int d = 0; d < 2; ++d) {
      float mx = acc[d * 5];
#pragma unroll
      for (int j = 1; j < 5; ++j) mx = fmaxf(mx, acc[d * 5 + j]);
      float e[5]; float ssum = 0.f;
#pragma unroll
      for (int j = 0; j < 5; ++j) { e[j] = __expf(acc[d * 5 + j] - mx); ssum += e[j]; }
      float r = 1.f / ssum;
#pragma unroll
      for (int j = 0; j < 5; ++j) attn[d * 5 + j] = e[j] * r;
    }
  }

  // ---- phase 3: deform for group g ----
  int l = l0 + pos;
  float acc16[16];
#pragma unroll
  for (int o = 0; o < 16; ++o) acc16[o] = 0.f;

#pragma unroll
  for (int d = 0; d < NDG; ++d) {
    const ushort* xr = xTb + (size_t)(g * 2 + d) * LL * 8;
#pragma unroll
    for (int k = 0; k < KK; ++k) {
      int lc = d * 5 + k;
      float off = offs[lc];
      float at  = attn[lc];
      float p   = (float)(l - 2 + k) + off;
      float p0f = floorf(p);
      float w1  = p - p0f;
      int p0 = (int)p0f;
      int p1 = p0 + 1;
      int i0 = min(max(p0, 0), LL - 1);
      int i1 = min(max(p1, 0), LL - 1);
      float f0 = (p0 >= 0 && p0 < LL) ? (1.f - w1) * at : 0.f;
      float f1 = (p1 >= 0 && p1 < LL) ? w1 * at : 0.f;
      uint4 u0 = *(const uint4*)(xr + (size_t)i0 * 8);
      uint4 u1 = *(const uint4*)(xr + (size_t)i1 * 8);
      float x0[8], x1[8];
      unpack8(u0.x, u0.y, u0.z, u0.w, x0);
      unpack8(u1.x, u1.y, u1.z, u1.w, x1);
#pragma unroll
      for (int c = 0; c < NCD; ++c) {
        float sv = x0[c] * f0 + x1[c] * f1;
        const float* wpc = wtW + g * 1280 + ((d * 8 + c) * 5 + k) * 16;
#pragma unroll
        for (int o4 = 0; o4 < 4; ++o4) {
          float4 w = *(const float4*)(wpc + (o4 << 2));
          acc16[(o4 << 2) + 0] += w.x * sv;
          acc16[(o4 << 2) + 1] += w.y * sv;
          acc16[(o4 << 2) + 2] += w.z * sv;
          acc16[(o4 << 2) + 3] += w.w * sv;
        }
      }
    }
  }

  float* op = out + (size_t)(b * NC + g * 16) * LL + l;
#pragma unroll
  for (int o = 0; o < 16; ++o)
    op[(size_t)o * LL] = acc16[o] + bias[g * 16 + o];
}

// ---------------------------------------------------------------------------
extern "C" void kernel_launch(void* const* d_in, const int* in_sizes, int n_in,
                              void* d_out, int out_size, void* d_ws, size_t ws_size,
                              hipStream_t stream)
{
  const float* x    = (const float*)d_in[0];
  const float* dwAw = (const float*)d_in[1];
  const float* dwAb = (const float*)d_in[2];
  const float* gnAw = (const float*)d_in[3];
  const float* gnAb = (const float*)d_in[4];
  const float* pwAw = (const float*)d_in[5];
  const float* pwAb = (const float*)d_in[6];
  const float* dwMw = (const float*)d_in[7];
  const float* dwMb = (const float*)d_in[8];
  const float* gnMw = (const float*)d_in[9];
  const float* gnMb = (const float*)d_in[10];
  const float* pwMw = (const float*)d_in[11];
  const float* pwMb = (const float*)d_in[12];
  const float* mw   = (const float*)d_in[13];
  const float* bias = (const float*)d_in[14];
  float* out = (float*)d_out;

  // ws (~34 MB): wtW 20K | wQA/wQM 96K each | bAf/bMf | partial | xT 33.5 MB
  float* wtW = (float*)d_ws;                       // 5120
  float* wQA = wtW + 5120;                         // 8*4*64*12 = 24576
  float* wQM = wQA + 24576;                        // 24576
  float* bAf = wQM + 24576;                        // 320
  float* bMf = bAf + 320;                          // 320
  float4* partial = (float4*)(bMf + 320);          // 512 float4
  ushort* xT = (ushort*)(partial + 512);           // 8*8*32768*8 ushort

  hipLaunchKernelGGL(k_stats, dim3(NB * NC), dim3(256), 0, stream,
                     x, dwAw, dwAb, dwMw, dwMb, partial);
  hipLaunchKernelGGL(k_xpose, dim3(NB * NGD * (LL / 256)), dim3(256), 0, stream,
                     x, xT);
  hipLaunchKernelGGL(k_fin2, dim3(9), dim3(256), 0, stream,
                     partial, gnAw, gnAb, gnMw, gnMb, pwAw, pwMw, pwAb, pwMb,
                     mw, wQA, wQM, bAf, bMf, wtW);
  hipLaunchKernelGGL(k_pd, dim3(NB * (LL / 128)), dim3(512), 0, stream,
                     xT, dwAw, dwAb, dwMw, dwMb, wQA, wQM, bAf, bMf,
                     wtW, bias, out);
}